// Round 1
// baseline (352.347 us; speedup 1.0000x reference)
//
#include <hip/hip_runtime.h>
#include <cmath>

// CP_LIF forward: spikes = scan over T of LIF recurrence.
//   v   = alpha*v + (1-alpha)*x_t        (f32, NO fma contraction -> match np/jax)
//   s   = (v - 1 > 0) ? 1 : 0            (forward of surrogate == hard step)
//   v  -= s * r                          (exact f32 subtract when s==1)
// alpha = exp(-1/tau), tau = softplus(tau_raw)+1e-3, r = softplus(r_raw)+1e-6
// Memory-bound streaming: 210 MB read + 210 MB write -> ~67 us floor @6.3 TB/s.

#define TSTEPS 100

__device__ __forceinline__ float softplus_once(float xr) {
  // true softplus rounded once to f32 (<=0.5 ulp from exact)
  double x = (double)xr;
  double sp = (x > 0.0) ? (x + log1p(exp(-x))) : log1p(exp(x));
  return (float)sp;
}

__global__ __launch_bounds__(256) void lif_fwd(
    const float* __restrict__ x,
    const float* __restrict__ tau_raw,
    const float* __restrict__ r_raw,
    float* __restrict__ out,
    int B, int N) {
#pragma clang fp contract(off)
  const int nq  = N >> 2;                       // float4 groups per row
  const int tid = blockIdx.x * blockDim.x + threadIdx.x;
  if (tid >= B * nq) return;
  const int n0 = (tid % nq) << 2;               // first neuron of this quad
  const int b  = tid / nq;

  // ---- per-neuron params (prologue, off critical path) ----
  float4 a4, o4, r4;
  {
    float av[4], ov[4], rv[4];
#pragma unroll
    for (int i = 0; i < 4; ++i) {
      float tau = softplus_once(tau_raw[n0 + i]) + 0.001f;
      float q   = -1.0f / tau;                  // f32 division as in jax (-DT/tau)
      float ai  = (float)exp((double)q);        // correctly-rounded exp of q
      av[i] = ai;
      ov[i] = 1.0f - ai;                        // exact (alpha in (0.5,1))
      rv[i] = softplus_once(r_raw[n0 + i]) + 1e-6f;
    }
    a4 = make_float4(av[0], av[1], av[2], av[3]);
    o4 = make_float4(ov[0], ov[1], ov[2], ov[3]);
    r4 = make_float4(rv[0], rv[1], rv[2], rv[3]);
  }

  const size_t base = (size_t)b * (size_t)N + (size_t)n0;
  const size_t str4 = ((size_t)B * (size_t)N) >> 2;   // float4 stride per t
  const float4* xp = (const float4*)x + (base >> 2);
  float4*       op = (float4*)out + (base >> 2);

  float4 v = make_float4(0.f, 0.f, 0.f, 0.f);

  // 2-deep register prefetch to cover HBM latency at 2 blocks/CU occupancy
  float4 c0 = xp[0];
  float4 c1 = xp[str4];
  const float4* xpre = xp + 2 * str4;

  for (int t = 0; t < TSTEPS; ++t) {
    float4 c2 = make_float4(0.f, 0.f, 0.f, 0.f);
    if (t + 2 < TSTEPS) c2 = *xpre;             // uniform branch
    xpre += str4;

    float4 s;
#define LIF_STEP(c)                                                  \
    {                                                                \
      float vn = a4.c * v.c + o4.c * c0.c;  /* mul,mul,add (no fma) */\
      float u  = vn - 1.0f;                                          \
      bool fire = u > 0.0f;                                          \
      s.c = fire ? 1.0f : 0.0f;                                      \
      v.c = fire ? (vn - r4.c) : vn;                                 \
    }
    LIF_STEP(x) LIF_STEP(y) LIF_STEP(z) LIF_STEP(w)
#undef LIF_STEP

    *op = s;
    op += str4;
    c0 = c1;
    c1 = c2;
  }
}

extern "C" void kernel_launch(void* const* d_in, const int* in_sizes, int n_in,
                              void* d_out, int out_size, void* d_ws, size_t ws_size,
                              hipStream_t stream) {
  const float* x       = (const float*)d_in[0];
  const float* tau_raw = (const float*)d_in[1];
  const float* r_raw   = (const float*)d_in[2];
  float*       out     = (float*)d_out;

  const int N = in_sizes[1];                    // 4096
  const int B = in_sizes[0] / (TSTEPS * N);     // 128

  const int threads = B * (N >> 2);             // 131072
  const int block   = 256;
  const int grid    = (threads + block - 1) / block;  // 512
  lif_fwd<<<grid, block, 0, stream>>>(x, tau_raw, r_raw, out, B, N);
}

// Round 4
// 338.720 us; speedup vs baseline: 1.0402x; 1.0402x over previous
//
#include <hip/hip_runtime.h>
#include <cmath>

// CP_LIF forward: spikes = scan over T of LIF recurrence.
//   v   = alpha*v + (1-alpha)*x_t        (f32, NO fma contraction -> match np/jax)
//   s   = (v - 1 > 0) ? 1 : 0            (forward of surrogate == hard step)
//   v  -= s * r                          (exact f32 subtract when s==1)
// Memory-bound streaming: 210 MB read + 210 MB write -> ~67 us floor @6.3 TB/s.
//
// R1..R3: latency-hiding rework. float2/thread (16 waves/CU, was 8), 4-deep
// statically-indexed register prefetch (no conditional loads in main loop),
// nontemporal load/store. Numerics identical to R0 (absmax was 0).
// R3 fix: __builtin_nontemporal_* requires a NATIVE vector type -> use
// ext_vector_type(2) float instead of HIP_vector_type float2.

#define TSTEPS 100
#define PF 4   // prefetch depth

typedef float f32x2 __attribute__((ext_vector_type(2)));

__device__ __forceinline__ float softplus_once(float xr) {
  // true softplus rounded once to f32 (<=0.5 ulp from exact)
  double x = (double)xr;
  double sp = (x > 0.0) ? (x + log1p(exp(-x))) : log1p(exp(x));
  return (float)sp;
}

__global__ __launch_bounds__(256) void lif_fwd(
    const float* __restrict__ x,
    const float* __restrict__ tau_raw,
    const float* __restrict__ r_raw,
    float* __restrict__ out,
    int B, int N) {
#pragma clang fp contract(off)
  const int nh  = N >> 1;                        // float2 groups per row
  const int tid = blockIdx.x * blockDim.x + threadIdx.x;
  if (tid >= B * nh) return;
  const int n0 = (tid % nh) << 1;                // first neuron of this pair
  const int b  = tid / nh;

  // ---- per-neuron params (prologue, off critical path) ----
  float a0, a1, o0, o1, r0, r1;
  {
    float tau = softplus_once(tau_raw[n0]) + 0.001f;
    a0 = (float)exp((double)(-1.0f / tau));      // f32 div, then CR exp
    o0 = 1.0f - a0;
    r0 = softplus_once(r_raw[n0]) + 1e-6f;
    tau = softplus_once(tau_raw[n0 + 1]) + 0.001f;
    a1 = (float)exp((double)(-1.0f / tau));
    o1 = 1.0f - a1;
    r1 = softplus_once(r_raw[n0 + 1]) + 1e-6f;
  }

  const size_t base2 = ((size_t)b * (size_t)N + (size_t)n0) >> 1;
  const size_t str2  = ((size_t)B * (size_t)N) >> 1;   // f32x2 stride per t
  const f32x2* xp = (const f32x2*)x + base2;
  f32x2*       op = (f32x2*)out + base2;

  float v0 = 0.f, v1 = 0.f;

  // ---- 4-deep register prefetch pipeline, all indices static ----
  f32x2 buf[PF];
#pragma unroll
  for (int j = 0; j < PF; ++j)
    buf[j] = __builtin_nontemporal_load(&xp[(size_t)j * str2]);
  const f32x2* xl = xp + (size_t)PF * str2;

#define LIF_STEP(c)                                               \
  {                                                               \
    f32x2 s;                                                      \
    {                                                             \
      float vn = a0 * v0 + o0 * (c)[0];  /* mul,mul,add: no fma */\
      float u  = vn - 1.0f;                                       \
      bool fire = u > 0.0f;                                       \
      s[0] = fire ? 1.0f : 0.0f;                                  \
      v0   = fire ? (vn - r0) : vn;                               \
    }                                                             \
    {                                                             \
      float vn = a1 * v1 + o1 * (c)[1];                           \
      float u  = vn - 1.0f;                                       \
      bool fire = u > 0.0f;                                       \
      s[1] = fire ? 1.0f : 0.0f;                                  \
      v1   = fire ? (vn - r1) : vn;                               \
    }                                                             \
    __builtin_nontemporal_store(s, op);                           \
    op += str2;                                                   \
  }

  // main loop: TSTEPS-PF iterations, unconditional prefetch
  for (int t = 0; t < TSTEPS - PF; t += PF) {
#pragma unroll
    for (int j = 0; j < PF; ++j) {
      f32x2 c = buf[j];
      buf[j] = __builtin_nontemporal_load(xl);
      xl += str2;
      LIF_STEP(c)
    }
  }
  // tail: last PF timesteps, no loads
#pragma unroll
  for (int j = 0; j < PF; ++j) {
    f32x2 c = buf[j];
    LIF_STEP(c)
  }
#undef LIF_STEP
}

extern "C" void kernel_launch(void* const* d_in, const int* in_sizes, int n_in,
                              void* d_out, int out_size, void* d_ws, size_t ws_size,
                              hipStream_t stream) {
  const float* x       = (const float*)d_in[0];
  const float* tau_raw = (const float*)d_in[1];
  const float* r_raw   = (const float*)d_in[2];
  float*       out     = (float*)d_out;

  const int N = in_sizes[1];                    // 4096
  const int B = in_sizes[0] / (TSTEPS * N);     // 128

  const int threads = B * (N >> 1);             // 262144
  if (threads <= 0) return;
  const int block   = 256;
  const int grid    = (threads + block - 1) / block;  // 1024
  lif_fwd<<<grid, block, 0, stream>>>(x, tau_raw, r_raw, out, B, N);
}